// Round 1
// baseline (718.264 us; speedup 1.0000x reference)
//
#include <hip/hip_runtime.h>
#include <stdint.h>

// ---------- types ----------
typedef __attribute__((ext_vector_type(8))) short short8;     // 8 bf16 (4 VGPRs) MFMA frag
typedef __attribute__((ext_vector_type(4))) float f32x4;      // MFMA acc
typedef __attribute__((ext_vector_type(4))) unsigned short us4;

// fp32 -> bf16 round-to-nearest-even (finite inputs only)
__device__ __forceinline__ unsigned short f2b(float f) {
  unsigned u = __builtin_bit_cast(unsigned, f);
  u = u + 0x7fffu + ((u >> 16) & 1u);
  return (unsigned short)(u >> 16);
}
__device__ __forceinline__ float b2f(unsigned short h) {
  unsigned u = ((unsigned)h) << 16;
  return __builtin_bit_cast(float, u);
}

// async global->LDS, 16B per lane (dst must be wave-uniform base + lane*16)
__device__ __forceinline__ void async_cp16(const unsigned short* g, unsigned short* l) {
  __builtin_amdgcn_global_load_lds(
      (const __attribute__((address_space(1))) void*)g,
      (__attribute__((address_space(3))) void*)l, 16, 0, 0);
}

// ---------- core GEMM: C[M,N] = A[M,K] * B[N,K]^T ----------
// SPLIT=1: A,B given as (hi,lo) bf16 planes; acc = Ah*Bh + Ah*Bl + Al*Bh.
// EPI: 0 = fp32 C0; 1 = bf16 C0; 2 = bf16 split (C0=hi, C1=lo).
// Tile 128x128, BK=32, 256 threads (4 waves, each 64x64 = 4x4 frags of 16x16).
// All dims must be multiples of 128 (true here: M in {1024,2048,4096,8192}, N=1024, K=1024).
template<int SPLIT, int EPI>
__global__ __launch_bounds__(256, 2)
void gemm_bt(const unsigned short* __restrict__ Ah, const unsigned short* __restrict__ Al,
             const unsigned short* __restrict__ Bh, const unsigned short* __restrict__ Bl,
             void* __restrict__ C0, void* __restrict__ C1,
             int K, int ldc, long aZ, long bZ, long cZ)
{
  __shared__ unsigned short sAh[128 * 32];
  __shared__ unsigned short sBh[128 * 32];
  __shared__ unsigned short sAl[SPLIT ? 128 * 32 : 8];
  __shared__ unsigned short sBl[SPLIT ? 128 * 32 : 8];

  const int t  = threadIdx.x;
  const int m0 = blockIdx.x * 128;
  const int n0 = blockIdx.y * 128;
  const int z  = blockIdx.z;

  const unsigned short* pAh = Ah + (long)z * aZ;
  const unsigned short* pBh = Bh + (long)z * bZ;
  const unsigned short* pAl = SPLIT ? (Al + (long)z * aZ) : (const unsigned short*)0;
  const unsigned short* pBl = SPLIT ? (Bl + (long)z * bZ) : (const unsigned short*)0;

  // staging: linear 16B chunks; chunk cid -> row = cid>>2, koff = (cid&3)*8
  const int rowS = t >> 2;
  const int kcS  = (t & 3) * 8;
  const long aOff0 = (long)(m0 + rowS) * K + kcS;
  const long aOff1 = (long)(m0 + rowS + 64) * K + kcS;
  const long bOff0 = (long)(n0 + rowS) * K + kcS;
  const long bOff1 = (long)(n0 + rowS + 64) * K + kcS;

  const int w  = t >> 6;
  const int l  = t & 63;
  const int wm = (w >> 1) * 64;
  const int wn = (w & 1) * 64;
  const int lm = l & 15;          // A: row m, B: row n, C: col n
  const int kq = (l >> 4) * 8;    // k offset within BK for A/B frags

  f32x4 acc[4][4];
  #pragma unroll
  for (int i = 0; i < 4; ++i)
    #pragma unroll
    for (int j = 0; j < 4; ++j)
      acc[i][j] = (f32x4){0.f, 0.f, 0.f, 0.f};

  for (int k0 = 0; k0 < K; k0 += 32) {
    async_cp16(pAh + aOff0 + k0, &sAh[t * 8]);
    async_cp16(pAh + aOff1 + k0, &sAh[(t + 256) * 8]);
    async_cp16(pBh + bOff0 + k0, &sBh[t * 8]);
    async_cp16(pBh + bOff1 + k0, &sBh[(t + 256) * 8]);
    if (SPLIT) {
      async_cp16(pAl + aOff0 + k0, &sAl[t * 8]);
      async_cp16(pAl + aOff1 + k0, &sAl[(t + 256) * 8]);
      async_cp16(pBl + bOff0 + k0, &sBl[t * 8]);
      async_cp16(pBl + bOff1 + k0, &sBl[(t + 256) * 8]);
    }
    __syncthreads();

    short8 bh[4], bl[4];
    #pragma unroll
    for (int j = 0; j < 4; ++j) {
      bh[j] = *(const short8*)&sBh[(wn + j * 16 + lm) * 32 + kq];
      if (SPLIT) bl[j] = *(const short8*)&sBl[(wn + j * 16 + lm) * 32 + kq];
    }
    #pragma unroll
    for (int i = 0; i < 4; ++i) {
      short8 ah = *(const short8*)&sAh[(wm + i * 16 + lm) * 32 + kq];
      short8 al;
      if (SPLIT) al = *(const short8*)&sAl[(wm + i * 16 + lm) * 32 + kq];
      #pragma unroll
      for (int j = 0; j < 4; ++j) {
        acc[i][j] = __builtin_amdgcn_mfma_f32_16x16x32_bf16(ah, bh[j], acc[i][j], 0, 0, 0);
        if (SPLIT) {
          acc[i][j] = __builtin_amdgcn_mfma_f32_16x16x32_bf16(ah, bl[j], acc[i][j], 0, 0, 0);
          acc[i][j] = __builtin_amdgcn_mfma_f32_16x16x32_bf16(al, bh[j], acc[i][j], 0, 0, 0);
        }
      }
    }
    __syncthreads();
  }

  // C/D layout (m89-verified): col = lane&15, row = (lane>>4)*4 + reg
  const int cr = wm + (l >> 4) * 4;
  const int cc = wn + lm;
  if (EPI == 0) {
    float* C = (float*)C0 + (long)z * cZ;
    #pragma unroll
    for (int i = 0; i < 4; ++i)
      #pragma unroll
      for (int j = 0; j < 4; ++j)
        #pragma unroll
        for (int r = 0; r < 4; ++r)
          C[(long)(m0 + cr + i * 16 + r) * ldc + (n0 + cc + j * 16)] = acc[i][j][r];
  } else if (EPI == 1) {
    unsigned short* C = (unsigned short*)C0 + (long)z * cZ;
    #pragma unroll
    for (int i = 0; i < 4; ++i)
      #pragma unroll
      for (int j = 0; j < 4; ++j)
        #pragma unroll
        for (int r = 0; r < 4; ++r)
          C[(long)(m0 + cr + i * 16 + r) * ldc + (n0 + cc + j * 16)] = f2b(acc[i][j][r]);
  } else {
    unsigned short* Ch = (unsigned short*)C0 + (long)z * cZ;
    unsigned short* Cl = (unsigned short*)C1 + (long)z * cZ;
    #pragma unroll
    for (int i = 0; i < 4; ++i)
      #pragma unroll
      for (int j = 0; j < 4; ++j)
        #pragma unroll
        for (int r = 0; r < 4; ++r) {
          float v = acc[i][j][r];
          unsigned short h = f2b(v);
          long idx = (long)(m0 + cr + i * 16 + r) * ldc + (n0 + cc + j * 16);
          Ch[idx] = h;
          Cl[idx] = f2b(v - b2f(h));
        }
  }
}

// ---------- fp32 -> (bf16 hi, bf16 lo) elementwise split; n must be /1024 ----------
__global__ __launch_bounds__(256)
void split_f32(const float* __restrict__ x, unsigned short* __restrict__ hi,
               unsigned short* __restrict__ lo)
{
  long i = ((long)blockIdx.x * 256 + threadIdx.x) * 4;
  float4 v = *(const float4*)(x + i);
  float vv[4] = {v.x, v.y, v.z, v.w};
  unsigned short hs[4], ls[4];
  #pragma unroll
  for (int k = 0; k < 4; ++k) {
    hs[k] = f2b(vv[k]);
    ls[k] = f2b(vv[k] - b2f(hs[k]));
  }
  *(us4*)(hi + i) = (us4){hs[0], hs[1], hs[2], hs[3]};
  *(us4*)(lo + i) = (us4){ls[0], ls[1], ls[2], ls[3]};
}

// ---------- weight transpose + split: W[1024,1024] -> WT_hi/lo[1024,1024] ----------
__global__ __launch_bounds__(256)
void wtrans(const float* __restrict__ w0, const float* __restrict__ w1,
            const float* __restrict__ w2,
            unsigned short* __restrict__ hiB, unsigned short* __restrict__ loB)
{
  __shared__ float tile[32][33];
  const int t = threadIdx.x;
  const int d0 = blockIdx.x * 32, h0 = blockIdx.y * 32, id = blockIdx.z;
  const float* W = (id == 0) ? w0 : ((id == 1) ? w1 : w2);
  unsigned short* hiW = hiB + (long)id * (1 << 20);
  unsigned short* loW = loB + (long)id * (1 << 20);
  #pragma unroll
  for (int p = 0; p < 4; ++p) {
    int dl = p * 8 + (t >> 5), hl = t & 31;
    tile[dl][hl] = W[(long)(d0 + dl) * 1024 + h0 + hl];
  }
  __syncthreads();
  #pragma unroll
  for (int p = 0; p < 4; ++p) {
    int hr = p * 8 + (t >> 5), dc = t & 31;
    float v = tile[dc][hr];
    unsigned short h = f2b(v);
    long off = (long)(h0 + hr) * 1024 + d0 + dc;
    hiW[off] = h;
    loW[off] = f2b(v - b2f(h));
  }
}

// ---------- row softmax: S fp32 [rows,1024] -> P bf16 [rows,1024] ----------
__global__ __launch_bounds__(256)
void softmax_rows(const float* __restrict__ S, unsigned short* __restrict__ P)
{
  const long row = blockIdx.x;
  const int t = threadIdx.x;
  float4 v = *(const float4*)(S + row * 1024 + t * 4);
  float m = fmaxf(fmaxf(v.x, v.y), fmaxf(v.z, v.w));
  #pragma unroll
  for (int off = 32; off > 0; off >>= 1) m = fmaxf(m, __shfl_down(m, off));
  __shared__ float red[4], red2[4];
  if ((t & 63) == 0) red[t >> 6] = m;
  __syncthreads();
  m = fmaxf(fmaxf(red[0], red[1]), fmaxf(red[2], red[3]));
  float e0 = __expf(v.x - m), e1 = __expf(v.y - m);
  float e2 = __expf(v.z - m), e3 = __expf(v.w - m);
  float sum = e0 + e1 + e2 + e3;
  #pragma unroll
  for (int off = 32; off > 0; off >>= 1) sum += __shfl_down(sum, off);
  if ((t & 63) == 0) red2[t >> 6] = sum;
  __syncthreads();
  float inv = 1.0f / (red2[0] + red2[1] + red2[2] + red2[3]);
  us4 o = {f2b(e0 * inv), f2b(e1 * inv), f2b(e2 * inv), f2b(e3 * inv)};
  *(us4*)(P + row * 1024 + t * 4) = o;
}

// ---------- host ----------
extern "C" void kernel_launch(void* const* d_in, const int* in_sizes, int n_in,
                              void* d_out, int out_size, void* d_ws, size_t ws_size,
                              hipStream_t stream)
{
  (void)in_sizes; (void)n_in; (void)out_size; (void)ws_size;
  // inputs: q [8,1024,1024], c [8,2048,1024], wq, wk, wv [1024,1024], all fp32
  const float* q  = (const float*)d_in[0];
  const float* c  = (const float*)d_in[1];
  const float* wq = (const float*)d_in[2];
  const float* wk = (const float*)d_in[3];
  const float* wv = (const float*)d_in[4];
  float* out = (float*)d_out;   // [8, 2048, 1024]; also serves as S scratch per batch pair

  char* ws = (char*)d_ws;
  size_t off = 0;
  auto alloc = [&](size_t bytes) -> void* {
    void* p = ws + off;
    off += (bytes + 255) & ~(size_t)255;
    return p;
  };
  // ws total: 132 MB
  unsigned short* wT_hi = (unsigned short*)alloc(3ull << 21);  // 3x [1024,1024] bf16 (wqT,wkT,wvT)
  unsigned short* wT_lo = (unsigned short*)alloc(3ull << 21);
  unsigned short* qhi   = (unsigned short*)alloc(8ull << 21);  // [8*1024,1024]
  unsigned short* qlo   = (unsigned short*)alloc(8ull << 21);
  unsigned short* Khi   = (unsigned short*)alloc(8ull << 21);  // [8*1024,1024]
  unsigned short* Klo   = (unsigned short*)alloc(8ull << 21);
  unsigned short* Vt    = (unsigned short*)alloc(8ull << 21);  // [8][1024(h),1024(lq)]
  unsigned short* chi   = (unsigned short*)alloc(4ull << 21);  // pair: [2*2048,1024]
  unsigned short* clo   = (unsigned short*)alloc(4ull << 21);
  unsigned short* Qhi   = (unsigned short*)alloc(4ull << 21);  // pair: [2*2048,1024]
  unsigned short* Qlo   = (unsigned short*)alloc(4ull << 21);
  unsigned short* Pb    = (unsigned short*)alloc(4ull << 21);  // pair: [2*2048,1024]

  // weights: transpose to [H,D] and split
  wtrans<<<dim3(32, 32, 3), 256, 0, stream>>>(wq, wk, wv, wT_hi, wT_lo);
  // q -> hi/lo (8M elems -> 8192 blocks)
  split_f32<<<8192, 256, 0, stream>>>(q, qhi, qlo);
  // Kproj (split): K = q @ wk : A=q[8192,1024], B=wkT[1024,1024] -> Khi/Klo
  gemm_bt<1, 2><<<dim3(64, 8, 1), 256, 0, stream>>>(
      qhi, qlo, wT_hi + (1l << 20), wT_lo + (1l << 20), Khi, Klo,
      1024, 1024, 0, 0, 0);
  // Vt (plain): Vt[b][h,l] = sum_d wvT[h,d]*q[b,l,d] : A=wvT, B=q[b] -> bf16
  gemm_bt<0, 1><<<dim3(8, 8, 8), 256, 0, stream>>>(
      wT_hi + (2l << 20), nullptr, qhi, nullptr, Vt, nullptr,
      1024, 1024, 0, 1l << 20, 1l << 20);

  for (int p = 0; p < 4; ++p) {  // batch pairs (2p, 2p+1)
    const float* cp = c + (size_t)p * (2 * 2048 * 1024);
    float* Sp = out + (size_t)p * (2 * 2048 * 1024);  // S scratch in d_out region
    // c pair -> hi/lo (4M elems -> 4096 blocks)
    split_f32<<<4096, 256, 0, stream>>>(cp, chi, clo);
    // Qproj (split): Q = c @ wq : A=c[4096,1024], B=wqT -> Qhi/Qlo
    gemm_bt<1, 2><<<dim3(32, 8, 1), 256, 0, stream>>>(
        chi, clo, wT_hi, wT_lo, Qhi, Qlo, 1024, 1024, 0, 0, 0);
    // QK^T (split): S[c,qt] = sum_h Q[c,h]*K[qt,h], z = batch within pair
    gemm_bt<1, 0><<<dim3(16, 8, 2), 256, 0, stream>>>(
        Qhi, Qlo, Khi + ((long)2 * p << 20), Klo + ((long)2 * p << 20), Sp, nullptr,
        1024, 1024, 1l << 21, 1l << 20, 1l << 21);
    // softmax rows -> P bf16
    softmax_rows<<<4096, 256, 0, stream>>>(Sp, Pb);
    // PV (plain): out[c,h] = sum_qt P[c,qt]*Vt[h,qt]
    gemm_bt<0, 0><<<dim3(16, 8, 2), 256, 0, stream>>>(
        Pb, nullptr, Vt + ((long)2 * p << 20), nullptr, Sp, nullptr,
        1024, 1024, 1l << 21, 1l << 20, 1l << 21);
  }
}

// Round 2
// 557.688 us; speedup vs baseline: 1.2879x; 1.2879x over previous
//
#include <hip/hip_runtime.h>
#include <stdint.h>

// ---------- types ----------
typedef __attribute__((ext_vector_type(8))) short short8;     // 8 bf16 (4 VGPRs) MFMA frag
typedef __attribute__((ext_vector_type(4))) float f32x4;      // MFMA acc
typedef __attribute__((ext_vector_type(4))) unsigned short us4;

// fp32 -> bf16 round-to-nearest-even (finite inputs only)
__device__ __forceinline__ unsigned short f2b(float f) {
  unsigned u = __builtin_bit_cast(unsigned, f);
  u = u + 0x7fffu + ((u >> 16) & 1u);
  return (unsigned short)(u >> 16);
}
__device__ __forceinline__ float b2f(unsigned short h) {
  unsigned u = ((unsigned)h) << 16;
  return __builtin_bit_cast(float, u);
}

// async global->LDS, 16B per lane (dst = wave-uniform base + lane*16)
__device__ __forceinline__ void async_cp16(const unsigned short* g, unsigned short* l) {
  __builtin_amdgcn_global_load_lds(
      (const __attribute__((address_space(1))) void*)g,
      (__attribute__((address_space(3))) void*)l, 16, 0, 0);
}

// ---------- core GEMM: C[M,N] = A[M,K] * B[N,K]^T ----------
// SPLIT=1: A,B given as (hi,lo) bf16 planes; acc = Ah*Bh + Ah*Bl + Al*Bh.
// EPI: 0 = fp32 C0; 1 = bf16 C0; 2 = bf16 split (C0=hi, C1=lo).
// Tile 128x128, BK=32, 256 threads (4 waves, each 64x64 = 4x4 frags of 16x16).
// LDS layout is XOR-swizzled: logical 16B chunk kc of row r lives at slot
// (kc + (r>>1)) & 3 within the row. Kills the 8-way bank conflict of the
// 64B-row-stride layout (rows alias mod 2 on 32 banks); post-swizzle each
// ds_read_b128 pass is exactly 2-way (free, m136).
template<int SPLIT, int EPI>
__global__ __launch_bounds__(256, 2)
void gemm_bt(const unsigned short* __restrict__ Ah, const unsigned short* __restrict__ Al,
             const unsigned short* __restrict__ Bh, const unsigned short* __restrict__ Bl,
             void* __restrict__ C0, void* __restrict__ C1,
             int K, int ldc, long aZ, long bZ, long cZ)
{
  __shared__ unsigned short sAh[128 * 32];
  __shared__ unsigned short sBh[128 * 32];
  __shared__ unsigned short sAl[SPLIT ? 128 * 32 : 8];
  __shared__ unsigned short sBl[SPLIT ? 128 * 32 : 8];

  const int t  = threadIdx.x;
  const int m0 = blockIdx.x * 128;
  const int n0 = blockIdx.y * 128;
  const int z  = blockIdx.z;

  const unsigned short* pAh = Ah + (long)z * aZ;
  const unsigned short* pBh = Bh + (long)z * bZ;
  const unsigned short* pAl = SPLIT ? (Al + (long)z * aZ) : (const unsigned short*)0;
  const unsigned short* pBl = SPLIT ? (Bl + (long)z * bZ) : (const unsigned short*)0;

  // staging: lane t -> physical (row = t>>2, slot = t&3); fetch logical chunk
  // kc = (slot - (row>>1)) & 3.  Row+64 has same (row>>1)&3 (64/2 % 4 == 0).
  const int rowS = t >> 2;
  const int kcS  = (((t & 3) - ((rowS >> 1) & 3)) & 3) * 8;
  const long aOff0 = (long)(m0 + rowS) * K + kcS;
  const long aOff1 = (long)(m0 + rowS + 64) * K + kcS;
  const long bOff0 = (long)(n0 + rowS) * K + kcS;
  const long bOff1 = (long)(n0 + rowS + 64) * K + kcS;

  const int w  = t >> 6;
  const int l  = t & 63;
  const int wm = (w >> 1) * 64;
  const int wn = (w & 1) * 64;
  const int lm = l & 15;          // A: row m, B: row n, C: col n
  const int kquad = l >> 4;       // logical k-chunk (8 elems) for A/B frags

  // loop-invariant swizzled LDS read offsets (elements)
  int offA[4], offB[4];
  #pragma unroll
  for (int i = 0; i < 4; ++i) {
    int r = wm + i * 16 + lm;
    offA[i] = r * 32 + ((kquad + (r >> 1)) & 3) * 8;
  }
  #pragma unroll
  for (int j = 0; j < 4; ++j) {
    int r = wn + j * 16 + lm;
    offB[j] = r * 32 + ((kquad + (r >> 1)) & 3) * 8;
  }

  f32x4 acc[4][4];
  #pragma unroll
  for (int i = 0; i < 4; ++i)
    #pragma unroll
    for (int j = 0; j < 4; ++j)
      acc[i][j] = (f32x4){0.f, 0.f, 0.f, 0.f};

  for (int k0 = 0; k0 < K; k0 += 32) {
    async_cp16(pAh + aOff0 + k0, &sAh[t * 8]);
    async_cp16(pAh + aOff1 + k0, &sAh[(t + 256) * 8]);
    async_cp16(pBh + bOff0 + k0, &sBh[t * 8]);
    async_cp16(pBh + bOff1 + k0, &sBh[(t + 256) * 8]);
    if (SPLIT) {
      async_cp16(pAl + aOff0 + k0, &sAl[t * 8]);
      async_cp16(pAl + aOff1 + k0, &sAl[(t + 256) * 8]);
      async_cp16(pBl + bOff0 + k0, &sBl[t * 8]);
      async_cp16(pBl + bOff1 + k0, &sBl[(t + 256) * 8]);
    }
    __syncthreads();

    short8 bh[4], bl[4];
    #pragma unroll
    for (int j = 0; j < 4; ++j) {
      bh[j] = *(const short8*)&sBh[offB[j]];
      if (SPLIT) bl[j] = *(const short8*)&sBl[offB[j]];
    }
    #pragma unroll
    for (int i = 0; i < 4; ++i) {
      short8 ah = *(const short8*)&sAh[offA[i]];
      short8 al;
      if (SPLIT) al = *(const short8*)&sAl[offA[i]];
      #pragma unroll
      for (int j = 0; j < 4; ++j) {
        acc[i][j] = __builtin_amdgcn_mfma_f32_16x16x32_bf16(ah, bh[j], acc[i][j], 0, 0, 0);
        if (SPLIT) {
          acc[i][j] = __builtin_amdgcn_mfma_f32_16x16x32_bf16(ah, bl[j], acc[i][j], 0, 0, 0);
          acc[i][j] = __builtin_amdgcn_mfma_f32_16x16x32_bf16(al, bh[j], acc[i][j], 0, 0, 0);
        }
      }
    }
    __syncthreads();
  }

  // C/D layout (m89-verified): col = lane&15, row = (lane>>4)*4 + reg
  const int cr = wm + (l >> 4) * 4;
  const int cc = wn + lm;
  if (EPI == 0) {
    float* C = (float*)C0 + (long)z * cZ;
    #pragma unroll
    for (int i = 0; i < 4; ++i)
      #pragma unroll
      for (int j = 0; j < 4; ++j)
        #pragma unroll
        for (int r = 0; r < 4; ++r)
          C[(long)(m0 + cr + i * 16 + r) * ldc + (n0 + cc + j * 16)] = acc[i][j][r];
  } else if (EPI == 1) {
    unsigned short* C = (unsigned short*)C0 + (long)z * cZ;
    #pragma unroll
    for (int i = 0; i < 4; ++i)
      #pragma unroll
      for (int j = 0; j < 4; ++j)
        #pragma unroll
        for (int r = 0; r < 4; ++r)
          C[(long)(m0 + cr + i * 16 + r) * ldc + (n0 + cc + j * 16)] = f2b(acc[i][j][r]);
  } else {
    unsigned short* Ch = (unsigned short*)C0 + (long)z * cZ;
    unsigned short* Cl = (unsigned short*)C1 + (long)z * cZ;
    #pragma unroll
    for (int i = 0; i < 4; ++i)
      #pragma unroll
      for (int j = 0; j < 4; ++j)
        #pragma unroll
        for (int r = 0; r < 4; ++r) {
          float v = acc[i][j][r];
          unsigned short h = f2b(v);
          long idx = (long)(m0 + cr + i * 16 + r) * ldc + (n0 + cc + j * 16);
          Ch[idx] = h;
          Cl[idx] = f2b(v - b2f(h));
        }
  }
}

// ---------- fp32 -> (bf16 hi, bf16 lo) elementwise split; 1024 elems/block ----------
__global__ __launch_bounds__(256)
void split_f32(const float* __restrict__ x, unsigned short* __restrict__ hi,
               unsigned short* __restrict__ lo)
{
  long i = ((long)blockIdx.x * 256 + threadIdx.x) * 4;
  float4 v = *(const float4*)(x + i);
  float vv[4] = {v.x, v.y, v.z, v.w};
  unsigned short hs[4], ls[4];
  #pragma unroll
  for (int k = 0; k < 4; ++k) {
    hs[k] = f2b(vv[k]);
    ls[k] = f2b(vv[k] - b2f(hs[k]));
  }
  *(us4*)(hi + i) = (us4){hs[0], hs[1], hs[2], hs[3]};
  *(us4*)(lo + i) = (us4){ls[0], ls[1], ls[2], ls[3]};
}

// ---------- weight transpose + split: W[1024,1024] -> WT_hi/lo[1024,1024] ----------
__global__ __launch_bounds__(256)
void wtrans(const float* __restrict__ w0, const float* __restrict__ w1,
            const float* __restrict__ w2,
            unsigned short* __restrict__ hiB, unsigned short* __restrict__ loB)
{
  __shared__ float tile[32][33];
  const int t = threadIdx.x;
  const int d0 = blockIdx.x * 32, h0 = blockIdx.y * 32, id = blockIdx.z;
  const float* W = (id == 0) ? w0 : ((id == 1) ? w1 : w2);
  unsigned short* hiW = hiB + (long)id * (1 << 20);
  unsigned short* loW = loB + (long)id * (1 << 20);
  #pragma unroll
  for (int p = 0; p < 4; ++p) {
    int dl = p * 8 + (t >> 5), hl = t & 31;
    tile[dl][hl] = W[(long)(d0 + dl) * 1024 + h0 + hl];
  }
  __syncthreads();
  #pragma unroll
  for (int p = 0; p < 4; ++p) {
    int hr = p * 8 + (t >> 5), dc = t & 31;
    float v = tile[dc][hr];
    unsigned short h = f2b(v);
    long off = (long)(h0 + hr) * 1024 + d0 + dc;
    hiW[off] = h;
    loW[off] = f2b(v - b2f(h));
  }
}

// ---------- row softmax: S fp32 [rows,1024] -> P bf16 [rows,1024] ----------
__global__ __launch_bounds__(256)
void softmax_rows(const float* __restrict__ S, unsigned short* __restrict__ P)
{
  const long row = blockIdx.x;
  const int t = threadIdx.x;
  float4 v = *(const float4*)(S + row * 1024 + t * 4);
  float m = fmaxf(fmaxf(v.x, v.y), fmaxf(v.z, v.w));
  #pragma unroll
  for (int off = 32; off > 0; off >>= 1) m = fmaxf(m, __shfl_down(m, off));
  __shared__ float red[4], red2[4];
  if ((t & 63) == 0) red[t >> 6] = m;
  __syncthreads();
  m = fmaxf(fmaxf(red[0], red[1]), fmaxf(red[2], red[3]));
  float e0 = __expf(v.x - m), e1 = __expf(v.y - m);
  float e2 = __expf(v.z - m), e3 = __expf(v.w - m);
  float sum = e0 + e1 + e2 + e3;
  #pragma unroll
  for (int off = 32; off > 0; off >>= 1) sum += __shfl_down(sum, off);
  if ((t & 63) == 0) red2[t >> 6] = sum;
  __syncthreads();
  float inv = 1.0f / (red2[0] + red2[1] + red2[2] + red2[3]);
  us4 o = {f2b(e0 * inv), f2b(e1 * inv), f2b(e2 * inv), f2b(e3 * inv)};
  *(us4*)(P + row * 1024 + t * 4) = o;
}

// ---------- host ----------
extern "C" void kernel_launch(void* const* d_in, const int* in_sizes, int n_in,
                              void* d_out, int out_size, void* d_ws, size_t ws_size,
                              hipStream_t stream)
{
  (void)in_sizes; (void)n_in; (void)out_size;
  // inputs: q [8,1024,1024], c [8,2048,1024], wq, wk, wv [1024,1024], all fp32
  const float* q  = (const float*)d_in[0];
  const float* c  = (const float*)d_in[1];
  const float* wq = (const float*)d_in[2];
  const float* wk = (const float*)d_in[3];
  const float* wv = (const float*)d_in[4];
  float* out = (float*)d_out;   // [8, 2048, 1024]; also S scratch per chunk

  const size_t MB = 1ull << 20;
  // chunk size: nb batches of c at a time. Full (nb=8) needs 188 MB; half (nb=4) 124 MB.
  const int nb = (ws_size >= 189 * MB) ? 8 : 4;
  const long cBatch = 2048l * 1024;   // c/Q/S/out elems per batch
  const long qBatch = 1024l * 1024;   // q/K/V elems per batch

  char* ws = (char*)d_ws;
  size_t off = 0;
  auto take = [&](size_t bytes) -> unsigned short* {
    unsigned short* p = (unsigned short*)(ws + off);
    off += bytes;
    return p;
  };
  unsigned short* wT_hi   = take(6 * MB);                 // 3x [1024,1024] bf16
  unsigned short* wT_lo   = take(6 * MB);
  size_t qsplitB  = 2 * (size_t)(8 * qBatch) * 2;         // 32 MB (hi+lo, all 8 batches)
  size_t QsplitB  = 2 * (size_t)(nb * cBatch) * 2;        // nb*8 MB
  unsigned short* regionA = take(QsplitB > qsplitB ? QsplitB : qsplitB);
  unsigned short* Khi     = take(16 * MB);                // [8*1024,1024]
  unsigned short* Klo     = take(16 * MB);
  unsigned short* Vt      = take(16 * MB);                // [8][1024(h),1024(lq)] bf16
  unsigned short* regionB = take((size_t)nb * 8 * MB);    // chi+clo; Pb aliases

  unsigned short* qhi = regionA;                 // [8192,1024]
  unsigned short* qlo = regionA + 8 * qBatch;
  unsigned short* Qhi = regionA;                 // [nb*2048,1024] (q-split dead by then)
  unsigned short* Qlo = regionA + nb * cBatch;
  unsigned short* chi = regionB;                 // [nb*2048,1024]
  unsigned short* clo = regionB + nb * cBatch;
  unsigned short* Pb  = regionB;                 // [nb*2048,1024] (c-split dead by then)

  // weights: transpose to [H,D] and split
  wtrans<<<dim3(32, 32, 3), 256, 0, stream>>>(wq, wk, wv, wT_hi, wT_lo);
  // q -> hi/lo (8M elems)
  split_f32<<<8192, 256, 0, stream>>>(q, qhi, qlo);
  // Kproj (split): K = q @ wk : A=q[8192,1024], B=wkT -> Khi/Klo
  gemm_bt<1, 2><<<dim3(64, 8, 1), 256, 0, stream>>>(
      qhi, qlo, wT_hi + (1l << 20), wT_lo + (1l << 20), Khi, Klo,
      1024, 1024, 0, 0, 0);
  // Vt (plain): Vt[b][h,l] = sum_d wvT[h,d]*q[b,l,d]
  gemm_bt<0, 1><<<dim3(8, 8, 8), 256, 0, stream>>>(
      wT_hi + (2l << 20), nullptr, qhi, nullptr, Vt, nullptr,
      1024, 1024, 0, qBatch, qBatch);

  for (int s0 = 0; s0 < 8; s0 += nb) {   // chunks of nb batches
    const float* cp = c + (size_t)s0 * cBatch;
    float* Sp = out + (size_t)s0 * cBatch;        // S scratch in d_out region
    // c chunk -> hi/lo
    split_f32<<<nb * 2048, 256, 0, stream>>>(cp, chi, clo);
    // Qproj (split): Q = c @ wq : A=c[nb*2048,1024], B=wqT -> Qhi/Qlo
    gemm_bt<1, 2><<<dim3(nb * 16, 8, 1), 256, 0, stream>>>(
        chi, clo, wT_hi, wT_lo, Qhi, Qlo, 1024, 1024, 0, 0, 0);
    // QK^T (split): S[c,qt] = sum_h Q[c,h]*K[qt,h], z = batch in chunk
    gemm_bt<1, 0><<<dim3(16, 8, nb), 256, 0, stream>>>(
        Qhi, Qlo, Khi + (long)s0 * qBatch, Klo + (long)s0 * qBatch, Sp, nullptr,
        1024, 1024, cBatch, qBatch, cBatch);
    // softmax rows -> P bf16
    softmax_rows<<<nb * 2048, 256, 0, stream>>>(Sp, Pb);
    // PV (plain): out[c,h] = sum_qt P[c,qt]*Vt[h,qt]
    gemm_bt<0, 0><<<dim3(16, 8, nb), 256, 0, stream>>>(
        Pb, nullptr, Vt + (long)s0 * qBatch, nullptr, Sp, nullptr,
        1024, 1024, cBatch, qBatch, cBatch);
  }
}

// Round 3
// 354.920 us; speedup vs baseline: 2.0237x; 1.5713x over previous
//
#include <hip/hip_runtime.h>
#include <stdint.h>

// ---------- types ----------
typedef _Float16 half8 __attribute__((ext_vector_type(8)));   // 8 fp16 (4 VGPRs) MFMA frag
typedef __attribute__((ext_vector_type(4))) float f32x4;      // MFMA acc
typedef __attribute__((ext_vector_type(4))) unsigned short us4;

__device__ __forceinline__ unsigned short f2h(float f) {
  _Float16 h = (_Float16)f;              // v_cvt_f16_f32, RTE
  return __builtin_bit_cast(unsigned short, h);
}

// async global->LDS, 16B per lane (dst = wave-uniform base + lane*16)
__device__ __forceinline__ void async_cp16(const unsigned short* g, unsigned short* l) {
  __builtin_amdgcn_global_load_lds(
      (const __attribute__((address_space(1))) void*)g,
      (__attribute__((address_space(3))) void*)l, 16, 0, 0);
}

// ---------- core GEMM: C[M,N] = A[M,K] * B[N,K]^T, fp16 in, fp32 acc ----------
// EPI: 0 = fp32 C; 1 = fp16 C.
// Tile 128x128, BK=32, 256 threads (4 waves, each 64x64 = 4x4 frags of 16x16).
// LDS XOR-swizzle (verified round 2: SQ_LDS_BANK_CONFLICT = 0): logical 16B
// chunk kc of row r lives at slot (kc + (r>>1)) & 3 within the row.
template<int EPI>
__global__ __launch_bounds__(256, 2)
void gemm_bt(const unsigned short* __restrict__ A, const unsigned short* __restrict__ B,
             void* __restrict__ C0,
             int K, int ldc, long aZ, long bZ, long cZ)
{
  __shared__ unsigned short sA[128 * 32];
  __shared__ unsigned short sB[128 * 32];

  const int t  = threadIdx.x;
  const int m0 = blockIdx.x * 128;
  const int n0 = blockIdx.y * 128;
  const int z  = blockIdx.z;

  const unsigned short* pA = A + (long)z * aZ;
  const unsigned short* pB = B + (long)z * bZ;

  // staging: lane t -> physical (row = t>>2, slot = t&3); fetch logical chunk
  // kc = (slot - (row>>1)) & 3.  Row+64 keeps the same ((row>>1)&3).
  const int rowS = t >> 2;
  const int kcS  = (((t & 3) - ((rowS >> 1) & 3)) & 3) * 8;
  const long aOff0 = (long)(m0 + rowS) * K + kcS;
  const long aOff1 = (long)(m0 + rowS + 64) * K + kcS;
  const long bOff0 = (long)(n0 + rowS) * K + kcS;
  const long bOff1 = (long)(n0 + rowS + 64) * K + kcS;

  const int w  = t >> 6;
  const int l  = t & 63;
  const int wm = (w >> 1) * 64;
  const int wn = (w & 1) * 64;
  const int lm = l & 15;          // A: row m, B: row n, C: col n
  const int kquad = l >> 4;       // logical 8-elem k-chunk for A/B frags

  // loop-invariant swizzled LDS read offsets (elements)
  int offA[4], offB[4];
  #pragma unroll
  for (int i = 0; i < 4; ++i) {
    int r = wm + i * 16 + lm;
    offA[i] = r * 32 + ((kquad + (r >> 1)) & 3) * 8;
  }
  #pragma unroll
  for (int j = 0; j < 4; ++j) {
    int r = wn + j * 16 + lm;
    offB[j] = r * 32 + ((kquad + (r >> 1)) & 3) * 8;
  }

  f32x4 acc[4][4];
  #pragma unroll
  for (int i = 0; i < 4; ++i)
    #pragma unroll
    for (int j = 0; j < 4; ++j)
      acc[i][j] = (f32x4){0.f, 0.f, 0.f, 0.f};

  for (int k0 = 0; k0 < K; k0 += 32) {
    async_cp16(pA + aOff0 + k0, &sA[t * 8]);
    async_cp16(pA + aOff1 + k0, &sA[(t + 256) * 8]);
    async_cp16(pB + bOff0 + k0, &sB[t * 8]);
    async_cp16(pB + bOff1 + k0, &sB[(t + 256) * 8]);
    __syncthreads();

    half8 bf[4];
    #pragma unroll
    for (int j = 0; j < 4; ++j)
      bf[j] = *(const half8*)&sB[offB[j]];
    #pragma unroll
    for (int i = 0; i < 4; ++i) {
      half8 af = *(const half8*)&sA[offA[i]];
      #pragma unroll
      for (int j = 0; j < 4; ++j)
        acc[i][j] = __builtin_amdgcn_mfma_f32_16x16x32_f16(af, bf[j], acc[i][j], 0, 0, 0);
    }
    __syncthreads();
  }

  // C/D layout (m89-verified): col = lane&15, row = (lane>>4)*4 + reg
  const int cr = wm + (l >> 4) * 4;
  const int cc = wn + lm;
  if (EPI == 0) {
    float* C = (float*)C0 + (long)z * cZ;
    #pragma unroll
    for (int i = 0; i < 4; ++i)
      #pragma unroll
      for (int j = 0; j < 4; ++j)
        #pragma unroll
        for (int r = 0; r < 4; ++r)
          C[(long)(m0 + cr + i * 16 + r) * ldc + (n0 + cc + j * 16)] = acc[i][j][r];
  } else {
    unsigned short* C = (unsigned short*)C0 + (long)z * cZ;
    #pragma unroll
    for (int i = 0; i < 4; ++i)
      #pragma unroll
      for (int j = 0; j < 4; ++j)
        #pragma unroll
        for (int r = 0; r < 4; ++r)
          C[(long)(m0 + cr + i * 16 + r) * ldc + (n0 + cc + j * 16)] = f2h(acc[i][j][r]);
  }
}

// ---------- fp32 -> fp16 elementwise convert; 1024 elems/block ----------
__global__ __launch_bounds__(256)
void cvt_f16(const float* __restrict__ x, unsigned short* __restrict__ y)
{
  long i = ((long)blockIdx.x * 256 + threadIdx.x) * 4;
  float4 v = *(const float4*)(x + i);
  *(us4*)(y + i) = (us4){f2h(v.x), f2h(v.y), f2h(v.z), f2h(v.w)};
}

// ---------- weight transpose + convert: W[1024,1024] fp32 -> WT[1024,1024] fp16 ----------
__global__ __launch_bounds__(256)
void wtrans(const float* __restrict__ w0, const float* __restrict__ w1,
            const float* __restrict__ w2, unsigned short* __restrict__ outB)
{
  __shared__ float tile[32][33];
  const int t = threadIdx.x;
  const int d0 = blockIdx.x * 32, h0 = blockIdx.y * 32, id = blockIdx.z;
  const float* W = (id == 0) ? w0 : ((id == 1) ? w1 : w2);
  unsigned short* WT = outB + (long)id * (1 << 20);
  #pragma unroll
  for (int p = 0; p < 4; ++p) {
    int dl = p * 8 + (t >> 5), hl = t & 31;
    tile[dl][hl] = W[(long)(d0 + dl) * 1024 + h0 + hl];
  }
  __syncthreads();
  #pragma unroll
  for (int p = 0; p < 4; ++p) {
    int hr = p * 8 + (t >> 5), dc = t & 31;
    WT[(long)(h0 + hr) * 1024 + d0 + dc] = f2h(tile[dc][hr]);
  }
}

// ---------- row softmax: S fp32 [rows,1024] -> P fp16 [rows,1024] ----------
__global__ __launch_bounds__(256)
void softmax_rows(const float* __restrict__ S, unsigned short* __restrict__ P)
{
  const long row = blockIdx.x;
  const int t = threadIdx.x;
  float4 v = *(const float4*)(S + row * 1024 + t * 4);
  float m = fmaxf(fmaxf(v.x, v.y), fmaxf(v.z, v.w));
  #pragma unroll
  for (int off = 32; off > 0; off >>= 1) m = fmaxf(m, __shfl_down(m, off));
  __shared__ float red[4], red2[4];
  if ((t & 63) == 0) red[t >> 6] = m;
  __syncthreads();
  m = fmaxf(fmaxf(red[0], red[1]), fmaxf(red[2], red[3]));
  float e0 = __expf(v.x - m), e1 = __expf(v.y - m);
  float e2 = __expf(v.z - m), e3 = __expf(v.w - m);
  float sum = e0 + e1 + e2 + e3;
  #pragma unroll
  for (int off = 32; off > 0; off >>= 1) sum += __shfl_down(sum, off);
  if ((t & 63) == 0) red2[t >> 6] = sum;
  __syncthreads();
  float inv = 1.0f / (red2[0] + red2[1] + red2[2] + red2[3]);
  us4 o = {f2h(e0 * inv), f2h(e1 * inv), f2h(e2 * inv), f2h(e3 * inv)};
  *(us4*)(P + row * 1024 + t * 4) = o;
}

// ---------- host ----------
extern "C" void kernel_launch(void* const* d_in, const int* in_sizes, int n_in,
                              void* d_out, int out_size, void* d_ws, size_t ws_size,
                              hipStream_t stream)
{
  (void)in_sizes; (void)n_in; (void)out_size; (void)ws_size;
  // inputs: q [8,1024,1024], c [8,2048,1024], wq, wk, wv [1024,1024], all fp32
  const float* q  = (const float*)d_in[0];
  const float* c  = (const float*)d_in[1];
  const float* wq = (const float*)d_in[2];
  const float* wk = (const float*)d_in[3];
  const float* wv = (const float*)d_in[4];
  float* out = (float*)d_out;   // [8, 2048, 1024]; also S scratch

  const size_t MB = 1ull << 20;
  const long cBatch = 2048l * 1024;   // c/Q/S/out elems per batch
  const long qBatch = 1024l * 1024;   // q/K/V elems per batch

  char* ws = (char*)d_ws;
  size_t off = 0;
  auto take = [&](size_t bytes) -> unsigned short* {
    unsigned short* p = (unsigned short*)(ws + off);
    off += bytes;
    return p;
  };
  // 118 MB total (ws >= 189 MB confirmed by round-2 full-batch path running)
  unsigned short* wT = take(6 * MB);    // 3x [1024(h),1024(d)] fp16: wqT, wkT, wvT
  unsigned short* qh = take(16 * MB);   // [8192,1024] fp16
  unsigned short* ch = take(32 * MB);   // [16384,1024] fp16; P aliases after Qproj
  unsigned short* Kf = take(16 * MB);   // [8192,1024] fp16
  unsigned short* Vt = take(16 * MB);   // [8][1024(h),1024(lq)] fp16
  unsigned short* Qf = take(32 * MB);   // [16384,1024] fp16
  unsigned short* Pf = ch;              // [16384,1024] fp16 (c-f16 dead after Qproj)

  // weights: transpose to [H,D], fp16
  wtrans<<<dim3(32, 32, 3), 256, 0, stream>>>(wq, wk, wv, wT);
  // q, c -> fp16
  cvt_f16<<<8192, 256, 0, stream>>>(q, qh);
  cvt_f16<<<16384, 256, 0, stream>>>(c, ch);
  // Kproj: K = q @ wk : A=qh[8192,1024], B=wkT[1024,1024]
  gemm_bt<1><<<dim3(64, 8, 1), 256, 0, stream>>>(
      qh, wT + (1l << 20), Kf, 1024, 1024, 0, 0, 0);
  // Vt (transposed): Vt[b][h,l] = sum_d wvT[h,d] * q[b,l,d]
  gemm_bt<1><<<dim3(8, 8, 8), 256, 0, stream>>>(
      wT + (2l << 20), qh, Vt, 1024, 1024, 0, qBatch, qBatch);
  // Qproj: Q = c @ wq : A=ch[16384,1024], B=wqT
  gemm_bt<1><<<dim3(128, 8, 1), 256, 0, stream>>>(
      ch, wT, Qf, 1024, 1024, 0, 0, 0);
  // QK^T: S[c,qt] = sum_h Q[c,h] * K[qt,h]  (S fp32 in d_out region)
  gemm_bt<0><<<dim3(16, 8, 8), 256, 0, stream>>>(
      Qf, Kf, out, 1024, 1024, cBatch, qBatch, cBatch);
  // softmax rows -> P fp16
  softmax_rows<<<16384, 256, 0, stream>>>(out, Pf);
  // PV: out[c,h] = sum_qt P[c,qt] * Vt[h,qt]
  gemm_bt<0><<<dim3(16, 8, 8), 256, 0, stream>>>(
      Pf, Vt, out, 1024, 1024, cBatch, qBatch, cBatch);
}

// Round 4
// 335.167 us; speedup vs baseline: 2.1430x; 1.0589x over previous
//
#include <hip/hip_runtime.h>
#include <stdint.h>

// ---------- types ----------
typedef _Float16 half8 __attribute__((ext_vector_type(8)));   // 8 fp16 (4 VGPRs) MFMA frag
typedef __attribute__((ext_vector_type(4))) float f32x4;      // MFMA acc
typedef __attribute__((ext_vector_type(4))) unsigned short us4;

__device__ __forceinline__ unsigned short f2h(float f) {
  _Float16 h = (_Float16)f;              // v_cvt_f16_f32, RTE
  return __builtin_bit_cast(unsigned short, h);
}

// async global->LDS, 16B per lane (dst = wave-uniform base + lane*16)
__device__ __forceinline__ void async_cp16(const unsigned short* g, unsigned short* l) {
  __builtin_amdgcn_global_load_lds(
      (const __attribute__((address_space(1))) void*)g,
      (__attribute__((address_space(3))) void*)l, 16, 0, 0);
}

// ---------- core GEMM: C[M,N] = A[M,K] * B[N,K]^T, fp16 in, fp32 acc ----------
// EPI: 0 = fp32 C; 1 = fp16 C.
// Tile 128x128, BK=64 (16 K-iterations for K=1024: half the barriers of BK=32),
// 256 threads (4 waves, each 64x64 = 4x4 frags of 16x16, 2 k-halves per iter).
// LDS XOR-swizzle for BK=64: row = 64 fp16 = 128 B = exactly 32 banks, so the
// logical 16B chunk kc of row r lives at slot (kc + r) & 7. Any 8 consecutive
// lanes in a ds_read_b128 phase then read 8 consecutive rows at 8 distinct
// slots -> all 32 banks, zero conflict (same model that gave measured 0
// conflicts in round 2).
template<int EPI>
__global__ __launch_bounds__(256, 2)
void gemm_bt(const unsigned short* __restrict__ A, const unsigned short* __restrict__ B,
             void* __restrict__ C0,
             int K, int ldc, long aZ, long bZ, long cZ)
{
  __shared__ unsigned short sA[128 * 64];   // 16 KB
  __shared__ unsigned short sB[128 * 64];   // 16 KB

  const int t  = threadIdx.x;
  const int m0 = blockIdx.x * 128;
  const int n0 = blockIdx.y * 128;
  const int z  = blockIdx.z;

  const unsigned short* pA = A + (long)z * aZ;
  const unsigned short* pB = B + (long)z * bZ;

  // staging: call ci (0..3) covers physical chunks pid = ci*256 + t.
  // pid -> row = pid>>3 = ci*32 + (t>>3), slot = t&7.
  // logical chunk kc = (slot - row) & 7 = ((t&7) - (t>>3)) & 7  (ci*32 % 8 == 0).
  const int rowS = t >> 3;
  const int kcS  = (((t & 7) - rowS) & 7) * 8;
  const long aBase = (long)(m0 + rowS) * K + kcS;
  const long bBase = (long)(n0 + rowS) * K + kcS;

  const int w  = t >> 6;
  const int l  = t & 63;
  const int wm = (w >> 1) * 64;
  const int wn = (w & 1) * 64;
  const int lm = l & 15;          // A: row m, B: row n, C: col n
  const int kquad = l >> 4;       // logical k-chunk (8 elems) within a k-half

  // loop-invariant swizzled LDS read offsets (elements), [frag][k-half]
  int offA[4][2], offB[4][2];
  #pragma unroll
  for (int i = 0; i < 4; ++i) {
    int r = wm + i * 16 + lm;
    #pragma unroll
    for (int kh = 0; kh < 2; ++kh)
      offA[i][kh] = r * 64 + ((kh * 4 + kquad + r) & 7) * 8;
  }
  #pragma unroll
  for (int j = 0; j < 4; ++j) {
    int r = wn + j * 16 + lm;
    #pragma unroll
    for (int kh = 0; kh < 2; ++kh)
      offB[j][kh] = r * 64 + ((kh * 4 + kquad + r) & 7) * 8;
  }

  f32x4 acc[4][4];
  #pragma unroll
  for (int i = 0; i < 4; ++i)
    #pragma unroll
    for (int j = 0; j < 4; ++j)
      acc[i][j] = (f32x4){0.f, 0.f, 0.f, 0.f};

  for (int k0 = 0; k0 < K; k0 += 64) {
    #pragma unroll
    for (int ci = 0; ci < 4; ++ci) {
      async_cp16(pA + aBase + (long)ci * 32 * K + k0, &sA[(ci * 256 + t) * 8]);
      async_cp16(pB + bBase + (long)ci * 32 * K + k0, &sB[(ci * 256 + t) * 8]);
    }
    __syncthreads();

    #pragma unroll
    for (int kh = 0; kh < 2; ++kh) {      // k-halves ascending: acc order == BK=32 version
      half8 bf[4];
      #pragma unroll
      for (int j = 0; j < 4; ++j)
        bf[j] = *(const half8*)&sB[offB[j][kh]];
      #pragma unroll
      for (int i = 0; i < 4; ++i) {
        half8 af = *(const half8*)&sA[offA[i][kh]];
        #pragma unroll
        for (int j = 0; j < 4; ++j)
          acc[i][j] = __builtin_amdgcn_mfma_f32_16x16x32_f16(af, bf[j], acc[i][j], 0, 0, 0);
      }
    }
    __syncthreads();
  }

  // C/D layout (m89-verified): col = lane&15, row = (lane>>4)*4 + reg
  const int cr = wm + (l >> 4) * 4;
  const int cc = wn + lm;
  if (EPI == 0) {
    float* C = (float*)C0 + (long)z * cZ;
    #pragma unroll
    for (int i = 0; i < 4; ++i)
      #pragma unroll
      for (int j = 0; j < 4; ++j)
        #pragma unroll
        for (int r = 0; r < 4; ++r)
          C[(long)(m0 + cr + i * 16 + r) * ldc + (n0 + cc + j * 16)] = acc[i][j][r];
  } else {
    unsigned short* C = (unsigned short*)C0 + (long)z * cZ;
    #pragma unroll
    for (int i = 0; i < 4; ++i)
      #pragma unroll
      for (int j = 0; j < 4; ++j)
        #pragma unroll
        for (int r = 0; r < 4; ++r)
          C[(long)(m0 + cr + i * 16 + r) * ldc + (n0 + cc + j * 16)] = f2h(acc[i][j][r]);
  }
}

// ---------- fp32 -> fp16 elementwise convert; 1024 elems/block ----------
__global__ __launch_bounds__(256)
void cvt_f16(const float* __restrict__ x, unsigned short* __restrict__ y)
{
  long i = ((long)blockIdx.x * 256 + threadIdx.x) * 4;
  float4 v = *(const float4*)(x + i);
  *(us4*)(y + i) = (us4){f2h(v.x), f2h(v.y), f2h(v.z), f2h(v.w)};
}

// ---------- weight transpose + convert: W[1024,1024] fp32 -> WT[1024,1024] fp16 ----------
__global__ __launch_bounds__(256)
void wtrans(const float* __restrict__ w0, const float* __restrict__ w1,
            const float* __restrict__ w2, unsigned short* __restrict__ outB)
{
  __shared__ float tile[32][33];
  const int t = threadIdx.x;
  const int d0 = blockIdx.x * 32, h0 = blockIdx.y * 32, id = blockIdx.z;
  const float* W = (id == 0) ? w0 : ((id == 1) ? w1 : w2);
  unsigned short* WT = outB + (long)id * (1 << 20);
  #pragma unroll
  for (int p = 0; p < 4; ++p) {
    int dl = p * 8 + (t >> 5), hl = t & 31;
    tile[dl][hl] = W[(long)(d0 + dl) * 1024 + h0 + hl];
  }
  __syncthreads();
  #pragma unroll
  for (int p = 0; p < 4; ++p) {
    int hr = p * 8 + (t >> 5), dc = t & 31;
    WT[(long)(h0 + hr) * 1024 + d0 + dc] = f2h(tile[dc][hr]);
  }
}

// ---------- row softmax: S fp32 [rows,1024] -> P fp16 [rows,1024] ----------
__global__ __launch_bounds__(256)
void softmax_rows(const float* __restrict__ S, unsigned short* __restrict__ P)
{
  const long row = blockIdx.x;
  const int t = threadIdx.x;
  float4 v = *(const float4*)(S + row * 1024 + t * 4);
  float m = fmaxf(fmaxf(v.x, v.y), fmaxf(v.z, v.w));
  #pragma unroll
  for (int off = 32; off > 0; off >>= 1) m = fmaxf(m, __shfl_down(m, off));
  __shared__ float red[4], red2[4];
  if ((t & 63) == 0) red[t >> 6] = m;
  __syncthreads();
  m = fmaxf(fmaxf(red[0], red[1]), fmaxf(red[2], red[3]));
  float e0 = __expf(v.x - m), e1 = __expf(v.y - m);
  float e2 = __expf(v.z - m), e3 = __expf(v.w - m);
  float sum = e0 + e1 + e2 + e3;
  #pragma unroll
  for (int off = 32; off > 0; off >>= 1) sum += __shfl_down(sum, off);
  if ((t & 63) == 0) red2[t >> 6] = sum;
  __syncthreads();
  float inv = 1.0f / (red2[0] + red2[1] + red2[2] + red2[3]);
  us4 o = {f2h(e0 * inv), f2h(e1 * inv), f2h(e2 * inv), f2h(e3 * inv)};
  *(us4*)(P + row * 1024 + t * 4) = o;
}

// ---------- host ----------
extern "C" void kernel_launch(void* const* d_in, const int* in_sizes, int n_in,
                              void* d_out, int out_size, void* d_ws, size_t ws_size,
                              hipStream_t stream)
{
  (void)in_sizes; (void)n_in; (void)out_size; (void)ws_size;
  // inputs: q [8,1024,1024], c [8,2048,1024], wq, wk, wv [1024,1024], all fp32
  const float* q  = (const float*)d_in[0];
  const float* c  = (const float*)d_in[1];
  const float* wq = (const float*)d_in[2];
  const float* wk = (const float*)d_in[3];
  const float* wv = (const float*)d_in[4];
  float* out = (float*)d_out;   // [8, 2048, 1024]; also S scratch

  const size_t MB = 1ull << 20;
  const long cBatch = 2048l * 1024;   // c/Q/S/out elems per batch
  const long qBatch = 1024l * 1024;   // q/K/V elems per batch

  char* ws = (char*)d_ws;
  size_t off = 0;
  auto take = [&](size_t bytes) -> unsigned short* {
    unsigned short* p = (unsigned short*)(ws + off);
    off += bytes;
    return p;
  };
  // 118 MB total
  unsigned short* wT = take(6 * MB);    // 3x [1024(h),1024(d)] fp16: wqT, wkT, wvT
  unsigned short* qh = take(16 * MB);   // [8192,1024] fp16
  unsigned short* ch = take(32 * MB);   // [16384,1024] fp16; P aliases after Qproj
  unsigned short* Kf = take(16 * MB);   // [8192,1024] fp16
  unsigned short* Vt = take(16 * MB);   // [8][1024(h),1024(lq)] fp16
  unsigned short* Qf = take(32 * MB);   // [16384,1024] fp16
  unsigned short* Pf = ch;              // [16384,1024] fp16 (c-f16 dead after Qproj)

  // weights: transpose to [H,D], fp16
  wtrans<<<dim3(32, 32, 3), 256, 0, stream>>>(wq, wk, wv, wT);
  // q, c -> fp16
  cvt_f16<<<8192, 256, 0, stream>>>(q, qh);
  cvt_f16<<<16384, 256, 0, stream>>>(c, ch);
  // Kproj: K = q @ wk : A=qh[8192,1024], B=wkT[1024,1024]
  gemm_bt<1><<<dim3(64, 8, 1), 256, 0, stream>>>(
      qh, wT + (1l << 20), Kf, 1024, 1024, 0, 0, 0);
  // Vt (transposed): Vt[b][h,l] = sum_d wvT[h,d] * q[b,l,d]
  gemm_bt<1><<<dim3(8, 8, 8), 256, 0, stream>>>(
      wT + (2l << 20), qh, Vt, 1024, 1024, 0, qBatch, qBatch);
  // Qproj: Q = c @ wq : A=ch[16384,1024], B=wqT
  gemm_bt<1><<<dim3(128, 8, 1), 256, 0, stream>>>(
      ch, wT, Qf, 1024, 1024, 0, 0, 0);
  // QK^T: S[c,qt] = sum_h Q[c,h] * K[qt,h]  (S fp32 in d_out region)
  gemm_bt<0><<<dim3(16, 8, 8), 256, 0, stream>>>(
      Qf, Kf, out, 1024, 1024, cBatch, qBatch, cBatch);
  // softmax rows -> P fp16
  softmax_rows<<<16384, 256, 0, stream>>>(out, Pf);
  // PV: out[c,h] = sum_qt P[c,qt] * Vt[h,qt]
  gemm_bt<0><<<dim3(16, 8, 8), 256, 0, stream>>>(
      Pf, Vt, out, 1024, 1024, cBatch, qBatch, cBatch);
}

// Round 5
// 315.988 us; speedup vs baseline: 2.2731x; 1.0607x over previous
//
#include <hip/hip_runtime.h>
#include <stdint.h>

// ---------- types ----------
typedef _Float16 half8 __attribute__((ext_vector_type(8)));   // 8 fp16 (4 VGPRs) MFMA frag
typedef __attribute__((ext_vector_type(4))) float f32x4;      // MFMA acc
typedef __attribute__((ext_vector_type(4))) unsigned short us4;

__device__ __forceinline__ unsigned short f2h(float f) {
  _Float16 h = (_Float16)f;              // v_cvt_f16_f32, RTE
  return __builtin_bit_cast(unsigned short, h);
}

// async global->LDS, 16B per lane (dst = wave-uniform base + lane*16)
__device__ __forceinline__ void async_cp16(const unsigned short* g, unsigned short* l) {
  __builtin_amdgcn_global_load_lds(
      (const __attribute__((address_space(1))) void*)g,
      (__attribute__((address_space(3))) void*)l, 16, 0, 0);
}

// ---------- core GEMM tile: C[m0:+128, n0:+128] = A[M,K] * B[N,K]^T ----------
// fp16 in, fp32 acc. EPI: 0 = fp32 C; 1 = fp16 C.
// Tile 128x128, BK=64 (16 K-iters at K=1024), 256 threads (4 waves, each
// 64x64 = 4x4 frags of 16x16, 2 k-halves per iter).
// LDS XOR-swizzle for BK=64 (round-4 verified: SQ_LDS_BANK_CONFLICT = 0):
// row = 64 fp16 = 128 B = 32 banks; logical 16B chunk kc of row r lives at
// slot (kc + r) & 7.
template<int EPI>
__device__ __forceinline__ void gemm_core(
    const unsigned short* __restrict__ pA, const unsigned short* __restrict__ pB,
    void* __restrict__ C0, int K, int ldc, int m0, int n0,
    unsigned short* sA, unsigned short* sB)
{
  const int t = threadIdx.x;

  // staging: call ci (0..3) covers physical chunks pid = ci*256 + t.
  // pid -> row = ci*32 + (t>>3), slot = t&7; logical kc = ((t&7)-(t>>3)) & 7.
  const int rowS = t >> 3;
  const int kcS  = (((t & 7) - rowS) & 7) * 8;
  const long aBase = (long)(m0 + rowS) * K + kcS;
  const long bBase = (long)(n0 + rowS) * K + kcS;

  const int w  = t >> 6;
  const int l  = t & 63;
  const int wm = (w >> 1) * 64;
  const int wn = (w & 1) * 64;
  const int lm = l & 15;          // A: row m, B: row n, C: col n
  const int kquad = l >> 4;       // logical k-chunk (8 elems) within a k-half

  // loop-invariant swizzled LDS read offsets (elements), [frag][k-half]
  int offA[4][2], offB[4][2];
  #pragma unroll
  for (int i = 0; i < 4; ++i) {
    int r = wm + i * 16 + lm;
    #pragma unroll
    for (int kh = 0; kh < 2; ++kh)
      offA[i][kh] = r * 64 + ((kh * 4 + kquad + r) & 7) * 8;
  }
  #pragma unroll
  for (int j = 0; j < 4; ++j) {
    int r = wn + j * 16 + lm;
    #pragma unroll
    for (int kh = 0; kh < 2; ++kh)
      offB[j][kh] = r * 64 + ((kh * 4 + kquad + r) & 7) * 8;
  }

  f32x4 acc[4][4];
  #pragma unroll
  for (int i = 0; i < 4; ++i)
    #pragma unroll
    for (int j = 0; j < 4; ++j)
      acc[i][j] = (f32x4){0.f, 0.f, 0.f, 0.f};

  for (int k0 = 0; k0 < K; k0 += 64) {
    #pragma unroll
    for (int ci = 0; ci < 4; ++ci) {
      async_cp16(pA + aBase + (long)ci * 32 * K + k0, &sA[(ci * 256 + t) * 8]);
      async_cp16(pB + bBase + (long)ci * 32 * K + k0, &sB[(ci * 256 + t) * 8]);
    }
    __syncthreads();

    #pragma unroll
    for (int kh = 0; kh < 2; ++kh) {      // k ascending: numerics fixed
      half8 bf[4];
      #pragma unroll
      for (int j = 0; j < 4; ++j)
        bf[j] = *(const half8*)&sB[offB[j][kh]];
      #pragma unroll
      for (int i = 0; i < 4; ++i) {
        half8 af = *(const half8*)&sA[offA[i][kh]];
        #pragma unroll
        for (int j = 0; j < 4; ++j)
          acc[i][j] = __builtin_amdgcn_mfma_f32_16x16x32_f16(af, bf[j], acc[i][j], 0, 0, 0);
      }
    }
    __syncthreads();
  }

  // C/D layout (m89-verified): col = lane&15, row = (lane>>4)*4 + reg
  const int cr = wm + (l >> 4) * 4;
  const int cc = wn + lm;
  if (EPI == 0) {
    float* C = (float*)C0;
    #pragma unroll
    for (int i = 0; i < 4; ++i)
      #pragma unroll
      for (int j = 0; j < 4; ++j)
        #pragma unroll
        for (int r = 0; r < 4; ++r)
          C[(long)(m0 + cr + i * 16 + r) * ldc + (n0 + cc + j * 16)] = acc[i][j][r];
  } else {
    unsigned short* C = (unsigned short*)C0;
    #pragma unroll
    for (int i = 0; i < 4; ++i)
      #pragma unroll
      for (int j = 0; j < 4; ++j)
        #pragma unroll
        for (int r = 0; r < 4; ++r)
          C[(long)(m0 + cr + i * 16 + r) * ldc + (n0 + cc + j * 16)] = f2h(acc[i][j][r]);
  }
}

// ---------- generic batched wrapper (QK^T, PV) ----------
template<int EPI>
__global__ __launch_bounds__(256, 2)
void gemm_bt(const unsigned short* __restrict__ A, const unsigned short* __restrict__ B,
             void* __restrict__ C0,
             int K, int ldc, long aZ, long bZ, long cZ)
{
  __shared__ unsigned short sA[128 * 64];   // 16 KB
  __shared__ unsigned short sB[128 * 64];   // 16 KB
  const long z = blockIdx.z;
  gemm_core<EPI>(A + z * aZ, B + z * bZ,
                 (EPI == 0) ? (void*)((float*)C0 + z * cZ)
                            : (void*)((unsigned short*)C0 + z * cZ),
                 K, ldc, blockIdx.x * 128, blockIdx.y * 128, sA, sB);
}

// ---------- merged projections: Qproj (1024 blocks) + Kproj (512) + Vproj (512) ----------
__global__ __launch_bounds__(256, 2)
void proj_all(const unsigned short* __restrict__ ch, const unsigned short* __restrict__ qh,
              const unsigned short* __restrict__ wT,
              unsigned short* __restrict__ Qf, unsigned short* __restrict__ Kf,
              unsigned short* __restrict__ Vt)
{
  __shared__ unsigned short sA[128 * 64];
  __shared__ unsigned short sB[128 * 64];
  const int bid = blockIdx.x;
  const long qBatch = 1024l * 1024;

  const unsigned short* pA;
  const unsigned short* pB;
  unsigned short* C;
  int m0, n0;
  if (bid < 1024) {                 // Qproj: Q = c @ wq  [16384,1024]
    pA = ch; pB = wT; C = Qf;
    m0 = (bid & 127) * 128; n0 = (bid >> 7) * 128;
  } else if (bid < 1536) {          // Kproj: K = q @ wk  [8192,1024]
    int i = bid - 1024;
    pA = qh; pB = wT + (1l << 20); C = Kf;
    m0 = (i & 63) * 128; n0 = (i >> 6) * 128;
  } else {                          // Vproj: Vt[z][h,l] = wvT @ q[z]^T  [8][1024,1024]
    int i = bid - 1536;
    long z = i >> 6;
    pA = wT + (2l << 20); pB = qh + z * qBatch; C = Vt + z * qBatch;
    m0 = (i & 7) * 128; n0 = ((i >> 3) & 7) * 128;
  }
  gemm_core<1>(pA, pB, C, 1024, 1024, m0, n0, sA, sB);
}

// ---------- merged prep: cvt_c (16384 blocks) + cvt_q (8192) + wtrans (3072) ----------
__global__ __launch_bounds__(256)
void prep_all(const float* __restrict__ q, const float* __restrict__ c,
              const float* __restrict__ wq, const float* __restrict__ wk,
              const float* __restrict__ wv,
              unsigned short* __restrict__ qh, unsigned short* __restrict__ ch,
              unsigned short* __restrict__ wT)
{
  __shared__ float tile[32][33];
  const int bid = blockIdx.x;
  const int t = threadIdx.x;

  if (bid < 24576) {                // fp32 -> fp16 convert, 1024 elems/block
    const float* x;
    unsigned short* y;
    long blk;
    if (bid < 16384) { x = c; y = ch; blk = bid; }
    else             { x = q; y = qh; blk = bid - 16384; }
    long i = (blk * 256 + t) * 4;
    float4 v = *(const float4*)(x + i);
    *(us4*)(y + i) = (us4){f2h(v.x), f2h(v.y), f2h(v.z), f2h(v.w)};
  } else {                          // weight transpose + convert
    int i = bid - 24576;
    const int d0 = (i & 31) * 32, h0 = ((i >> 5) & 31) * 32, id = i >> 10;
    const float* W = (id == 0) ? wq : ((id == 1) ? wk : wv);
    unsigned short* WT = wT + (long)id * (1 << 20);
    #pragma unroll
    for (int p = 0; p < 4; ++p) {
      int dl = p * 8 + (t >> 5), hl = t & 31;
      tile[dl][hl] = W[(long)(d0 + dl) * 1024 + h0 + hl];
    }
    __syncthreads();
    #pragma unroll
    for (int p = 0; p < 4; ++p) {
      int hr = p * 8 + (t >> 5), dc = t & 31;
      WT[(long)(h0 + hr) * 1024 + d0 + dc] = f2h(tile[dc][hr]);
    }
  }
}

// ---------- row softmax: S fp32 [rows,1024] -> P fp16 [rows,1024] ----------
__global__ __launch_bounds__(256)
void softmax_rows(const float* __restrict__ S, unsigned short* __restrict__ P)
{
  const long row = blockIdx.x;
  const int t = threadIdx.x;
  float4 v = *(const float4*)(S + row * 1024 + t * 4);
  float m = fmaxf(fmaxf(v.x, v.y), fmaxf(v.z, v.w));
  #pragma unroll
  for (int off = 32; off > 0; off >>= 1) m = fmaxf(m, __shfl_down(m, off));
  __shared__ float red[4], red2[4];
  if ((t & 63) == 0) red[t >> 6] = m;
  __syncthreads();
  m = fmaxf(fmaxf(red[0], red[1]), fmaxf(red[2], red[3]));
  float e0 = __expf(v.x - m), e1 = __expf(v.y - m);
  float e2 = __expf(v.z - m), e3 = __expf(v.w - m);
  float sum = e0 + e1 + e2 + e3;
  #pragma unroll
  for (int off = 32; off > 0; off >>= 1) sum += __shfl_down(sum, off);
  if ((t & 63) == 0) red2[t >> 6] = sum;
  __syncthreads();
  float inv = 1.0f / (red2[0] + red2[1] + red2[2] + red2[3]);
  us4 o = {f2h(e0 * inv), f2h(e1 * inv), f2h(e2 * inv), f2h(e3 * inv)};
  *(us4*)(P + row * 1024 + t * 4) = o;
}

// ---------- host ----------
extern "C" void kernel_launch(void* const* d_in, const int* in_sizes, int n_in,
                              void* d_out, int out_size, void* d_ws, size_t ws_size,
                              hipStream_t stream)
{
  (void)in_sizes; (void)n_in; (void)out_size; (void)ws_size;
  // inputs: q [8,1024,1024], c [8,2048,1024], wq, wk, wv [1024,1024], all fp32
  const float* q  = (const float*)d_in[0];
  const float* c  = (const float*)d_in[1];
  const float* wq = (const float*)d_in[2];
  const float* wk = (const float*)d_in[3];
  const float* wv = (const float*)d_in[4];
  float* out = (float*)d_out;   // [8, 2048, 1024]; also S scratch

  const size_t MB = 1ull << 20;
  const long cBatch = 2048l * 1024;   // c/Q/S/out elems per batch
  const long qBatch = 1024l * 1024;   // q/K/V elems per batch

  char* ws = (char*)d_ws;
  size_t off = 0;
  auto take = [&](size_t bytes) -> unsigned short* {
    unsigned short* p = (unsigned short*)(ws + off);
    off += bytes;
    return p;
  };
  // 118 MB total
  unsigned short* wT = take(6 * MB);    // 3x [1024(h),1024(d)] fp16: wqT, wkT, wvT
  unsigned short* qh = take(16 * MB);   // [8192,1024] fp16
  unsigned short* ch = take(32 * MB);   // [16384,1024] fp16; P aliases after Qproj
  unsigned short* Kf = take(16 * MB);   // [8192,1024] fp16
  unsigned short* Vt = take(16 * MB);   // [8][1024(h),1024(lq)] fp16
  unsigned short* Qf = take(32 * MB);   // [16384,1024] fp16
  unsigned short* Pf = ch;              // [16384,1024] fp16 (c-f16 dead after Qproj)

  // 1) prep: c->fp16, q->fp16, weights transpose->fp16
  prep_all<<<27648, 256, 0, stream>>>(q, c, wq, wk, wv, qh, ch, wT);
  // 2) all three projections in one dispatch (2048 blocks)
  proj_all<<<2048, 256, 0, stream>>>(ch, qh, wT, Qf, Kf, Vt);
  // 3) QK^T: S[c,qt] = sum_h Q[c,h] * K[qt,h]  (S fp32 in d_out region)
  gemm_bt<0><<<dim3(16, 8, 8), 256, 0, stream>>>(
      Qf, Kf, out, 1024, 1024, cBatch, qBatch, cBatch);
  // 4) softmax rows -> P fp16
  softmax_rows<<<16384, 256, 0, stream>>>(out, Pf);
  // 5) PV: out[c,h] = sum_qt P[c,qt] * Vt[h,qt]
  gemm_bt<0><<<dim3(16, 8, 8), 256, 0, stream>>>(
      Pf, Vt, out, 1024, 1024, cBatch, qBatch, cBatch);
}